// Round 4
// baseline (382.774 us; speedup 1.0000x reference)
//
#include <hip/hip_runtime.h>
#include <math.h>

#define NROWS 262144
#define DIM   256
#define NC    64
#define CD    (NC*DIM)       // 16384 floats = 64 KB
#define T1    512
#define NBLK  512

// ws float-offset layout:
//  A: acc fallback [CD]      @ 0
//  B: s_part [NBLK*64]       @ 16384
//  C: cent_new [CD]          @ 49152
//  D: s_final [64]           @ 65536
//  E: abs_part [256]         @ 65600
//  F: pair_part [64]         @ 65856
//  G: partials [P*CD]        @ 65920
#define OFF_S     16384
#define OFF_CENT  49152
#define OFF_SF    65536
#define OFF_ABS   65600
#define OFF_PAIR  65856
#define OFF_PART  65920

// DPP-based 64-lane sum: after these 6 adds, lane 63 holds the full sum.
#define DPP_ADD(v, ctrl) \
    ((v) + __int_as_float(__builtin_amdgcn_update_dpp(0, __float_as_int(v), (ctrl), 0xf, 0xf, true)))

__global__ __launch_bounds__(T1, 4)
void k1_main(const float* __restrict__ pred, const float* __restrict__ cent,
             const float* __restrict__ count, const int* __restrict__ tgt,
             float* __restrict__ ws, int P)
{
    __shared__ float acc[CD];
    __shared__ float s_lds[NC];
    const int tid  = threadIdx.x;
    const int wave = tid >> 6;
    const int lane = tid & 63;
    for (int o = tid; o < CD; o += T1) acc[o] = 0.f;
    if (tid < NC) s_lds[tid] = 0.f;

    const int base = (blockIdx.x * 8 + wave) * 64;     // 64 rows for this wave
    const int   t_reg      = tgt[base + lane];         // targets of rows base..base+63
    const float invrow_reg = 1.0f / count[t_reg];      // 1/count for row (base+lane)
    __syncthreads();

    const float4* pred4 = (const float4*)pred;
    const float4* cent4 = (const float4*)cent;

    // 4-slot software pipeline; all slot arrays statically indexed via unroll.
    int    c_[4];
    float  inv_[4];
    float4 p_[4], e_[4];
    #pragma unroll
    for (int k = 0; k < 4; ++k) {
        c_[k]   = __shfl(t_reg, k, 64);
        inv_[k] = __shfl(invrow_reg, k, 64);
        p_[k]   = pred4[(size_t)(base + k) * 64 + lane];
        e_[k]   = cent4[(size_t)c_[k] * 64 + lane];
    }

    #pragma unroll 1
    for (int r = 0; r < 64; r += 4) {
        const bool pf = (r + 4 < 64);
        #pragma unroll
        for (int k = 0; k < 4; ++k) {
            const int    c   = c_[k];
            const float  inv = inv_[k];
            const float4 p   = p_[k];
            const float4 e   = e_[k];
            if (pf) {                      // prefetch row r+4+k into slot k
                const int rn = r + 4 + k;
                c_[k]   = __shfl(t_reg, rn, 64);
                inv_[k] = __shfl(invrow_reg, rn, 64);
                p_[k]   = pred4[(size_t)(base + rn) * 64 + lane];
                e_[k]   = cent4[(size_t)c_[k] * 64 + lane];
            }
            const float prx = p.x * inv, pry = p.y * inv;
            const float prz = p.z * inv, prw = p.w * inv;
            // conflict-free, collision-free LDS accumulate (c wave-uniform):
            // element d = 4*lane + k stored at c*256 + k*64 + lane
            const int ab = (c << 8) + lane;
            unsafeAtomicAdd(&acc[ab      ], prx);
            unsafeAtomicAdd(&acc[ab +  64], pry);
            unsafeAtomicAdd(&acc[ab + 128], prz);
            unsafeAtomicAdd(&acc[ab + 192], prw);
            const float dx = e.x - prx, dy = e.y - pry;
            const float dz = e.z - prz, dw = e.w - prw;
            float ss = dx*dx + dy*dy + dz*dz + dw*dw;
            // 64-lane DPP reduction -> lane 63
            ss = DPP_ADD(ss, 0x111);   // row_shr:1
            ss = DPP_ADD(ss, 0x112);   // row_shr:2
            ss = DPP_ADD(ss, 0x114);   // row_shr:4
            ss = DPP_ADD(ss, 0x118);   // row_shr:8
            ss = DPP_ADD(ss, 0x142);   // row_bcast:15
            ss = DPP_ADD(ss, 0x143);   // row_bcast:31
            if (lane == 63) unsafeAtomicAdd(&s_lds[c], sqrtf(ss));
        }
    }
    __syncthreads();

    // flush
    if (tid < NC) ws[OFF_S + blockIdx.x * 64 + tid] = s_lds[tid];
    if (P > 0) {
        float4*       dst = (float4*)(ws + OFF_PART + (size_t)blockIdx.x * CD);
        const float4* src = (const float4*)acc;
        for (int o = tid; o < CD / 4; o += T1) dst[o] = src[o];
    } else {
        for (int o = tid; o < CD; o += T1) unsafeAtomicAdd(&ws[o], acc[o]);
    }
}

__global__ __launch_bounds__(512)
void k2_reduce(const float* __restrict__ cent, const float* __restrict__ count,
               const float* __restrict__ dist, float* __restrict__ ws, int P)
{
    const int tid = threadIdx.x;              // 0..511
    const int sub = tid & 63;
    const int g   = tid >> 6;                 // 0..7
    const int o   = blockIdx.x * 64 + sub;    // storage index 0..16383

    float sum = 0.f;
    if (P > 0) {
        const float* gp = ws + OFF_PART;
        #pragma unroll 4
        for (int p = g; p < P; p += 8) sum += gp[(size_t)p * CD + o];
    } else if (g == 0) {
        sum = ws[o];
    }
    __shared__ float red[8][64];
    red[g][sub] = sum;
    __syncthreads();

    if (tid < 64) {
        float tot = 0.f;
        #pragma unroll
        for (int q = 0; q < 8; ++q) tot += red[q][tid];
        const int oo = blockIdx.x * 64 + tid;     // storage index
        const int c  = oo >> 8;
        const int s  = oo & 255;                  // k*64 + l
        const int dd = ((s & 63) << 2) | (s >> 6);// d = 4*l + k
        float val = cent[c * 256 + dd] + tot;     // tot is sum of pr already
        ws[OFF_CENT + c * 256 + dd] = val;
        float a = fabsf(val);
        #pragma unroll
        for (int off = 32; off > 0; off >>= 1) a += __shfl_xor(a, off, 64);
        if (tid == 0) ws[OFF_ABS + blockIdx.x] = a;
    }

    if (blockIdx.x == 0) {
        __shared__ float sred[8][64];
        float ssum = 0.f;
        #pragma unroll 4
        for (int b = g; b < NBLK; b += 8) ssum += ws[OFF_S + b * 64 + sub];
        sred[g][sub] = ssum;
        __syncthreads();
        if (tid < 64) {
            float s_tot = 0.f;
            #pragma unroll
            for (int q = 0; q < 8; ++q) s_tot += sred[q][tid];
            ws[OFF_SF + tid] = sqrtf(dist[tid] + s_tot) / count[tid];
        }
    }
}

__global__ __launch_bounds__(256)
void k3_pairs(const float* __restrict__ cw, float* __restrict__ ws)
{
    const int i    = blockIdx.x;
    const int tid  = threadIdx.x;
    const int lane = tid & 63;
    const int w    = tid >> 6;
    const float4* c4 = (const float4*)(ws + OFF_CENT);
    const float*  sf = ws + OFF_SF;

    float4 ci = c4[i * 64 + lane];
    float  si = sf[i];
    float acc = 0.f;
    for (int j = w; j < NC; j += 4) {
        if (j == i) continue;
        float4 cj = c4[j * 64 + lane];
        float dx = ci.x - cj.x, dy = ci.y - cj.y;
        float dz = ci.z - cj.z, dw = ci.w - cj.w;
        float ss = dx*dx + dy*dy + dz*dz + dw*dw;
        #pragma unroll
        for (int o = 32; o > 0; o >>= 1) ss += __shfl_xor(ss, o, 64);
        float m = sqrtf(ss);
        acc += cw[i * NC + j] * (si + sf[j]) / m;
    }
    __shared__ float wsum[4];
    if (lane == 0) wsum[w] = acc;
    __syncthreads();
    if (tid == 0) ws[OFF_PAIR + i] = wsum[0] + wsum[1] + wsum[2] + wsum[3];
}

__global__ __launch_bounds__(256)
void k4_final(const float* __restrict__ ws, float* __restrict__ out)
{
    const int t = threadIdx.x;   // 256 threads
    float a = ws[OFF_ABS + t];
    float p = (t < 64) ? ws[OFF_PAIR + t] : 0.f;
    #pragma unroll
    for (int o = 32; o > 0; o >>= 1) {
        a += __shfl_xor(a, o, 64);
        p += __shfl_xor(p, o, 64);
    }
    __shared__ float ra[4], rp[4];
    if ((t & 63) == 0) { ra[t >> 6] = a; rp[t >> 6] = p; }
    __syncthreads();
    if (t == 0) {
        float pair_sum = rp[0] + rp[1] + rp[2] + rp[3];
        float abs_sum  = ra[0] + ra[1] + ra[2] + ra[3];
        out[0] = pair_sum / 64.0f * 63.0f + abs_sum * 1e-6f;
    }
}

extern "C" void kernel_launch(void* const* d_in, const int* in_sizes, int n_in,
                              void* d_out, int out_size, void* d_ws, size_t ws_size,
                              hipStream_t stream)
{
    const float* pred  = (const float*)d_in[0];
    const float* cent  = (const float*)d_in[1];
    const float* dist  = (const float*)d_in[2];
    const float* count = (const float*)d_in[3];
    const float* cw    = (const float*)d_in[4];
    const int*   tgt   = (const int*)d_in[5];
    float* ws  = (float*)d_ws;
    float* out = (float*)d_out;

    long ws_f  = (long)(ws_size / sizeof(float));
    long avail = ws_f - OFF_PART;
    int P = (avail >= (long)NBLK * CD) ? NBLK : 0;

    // zero only the atomic-fallback region A (s region is overwritten)
    hipMemsetAsync(d_ws, 0, (size_t)CD * sizeof(float), stream);

    k1_main<<<NBLK, T1, 0, stream>>>(pred, cent, count, tgt, ws, P);
    k2_reduce<<<256, 512, 0, stream>>>(cent, count, dist, ws, P);
    k3_pairs<<<NC, 256, 0, stream>>>(cw, ws);
    k4_final<<<1, 256, 0, stream>>>(ws, out);
}

// Round 5
// 98.585 us; speedup vs baseline: 3.8827x; 3.8827x over previous
//
#include <hip/hip_runtime.h>
#include <math.h>

#define NROWS 262144
#define DIM   256
#define NC    64
#define CD    (NC*DIM)       // 16384 floats = 64 KB
#define T1    512
#define NBLK  512

// ws float-offset layout:
//  A: acc fallback [CD]      @ 0
//  B: s_part [NBLK*64]       @ 16384
//  C: cent_new [CD]          @ 49152
//  D: s_final [64]           @ 65536
//  E: abs_part [256]         @ 65600
//  F: pair_part [64]         @ 65856
//  G: partials [P*CD]        @ 65920
#define OFF_S     16384
#define OFF_CENT  49152
#define OFF_SF    65536
#define OFF_ABS   65600
#define OFF_PAIR  65856
#define OFF_PART  65920

// DPP 64-lane sum: after these 6 adds, lane 63 holds the full sum.
#define DPP_ADD(v, ctrl) \
    ((v) + __int_as_float(__builtin_amdgcn_update_dpp(0, __float_as_int(v), (ctrl), 0xf, 0xf, true)))

__device__ __forceinline__ float dpp_sum64(float v) {
    v = DPP_ADD(v, 0x111);   // row_shr:1
    v = DPP_ADD(v, 0x112);   // row_shr:2
    v = DPP_ADD(v, 0x114);   // row_shr:4
    v = DPP_ADD(v, 0x118);   // row_shr:8
    v = DPP_ADD(v, 0x142);   // row_bcast:15
    v = DPP_ADD(v, 0x143);   // row_bcast:31
    return v;                // lane 63 = total
}

// k1: NO LDS, NO atomics in the hot path. Wave w owns classes [8w,8w+8).
// Per 64-row chunk: ballot per owned class, walk the mask, accumulate into
// statically-indexed register accumulators.
__global__ __launch_bounds__(T1)
void k1_main(const float* __restrict__ pred, const float* __restrict__ cent,
             const float* __restrict__ count, const int* __restrict__ tgt,
             float* __restrict__ ws, int P)
{
    const int tid  = threadIdx.x;
    const int wave = tid >> 6;
    const int lane = tid & 63;
    const int rowbase = blockIdx.x * 512;      // 512 rows per block
    const int cls0    = wave * 8;              // first owned class

    const float4* pred4 = (const float4*)pred;
    const float4* cent4 = (const float4*)cent;

    float4 acc[8];
    float4 ck_[8];
    float  inv_[8];
    float  sacc[8];
    #pragma unroll
    for (int k = 0; k < 8; ++k) {
        acc[k]  = make_float4(0.f, 0.f, 0.f, 0.f);
        ck_[k]  = cent4[(size_t)(cls0 + k) * 64 + lane];
        inv_[k] = 1.0f / count[cls0 + k];
        sacc[k] = 0.f;
    }

    for (int ch = 0; ch < 8; ++ch) {
        const int rb    = rowbase + ch * 64;
        const int t_reg = tgt[rb + lane];
        #pragma unroll
        for (int k = 0; k < 8; ++k) {
            unsigned long long m = __ballot(t_reg == cls0 + k);
            const float  ivk = inv_[k];
            const float4 ck  = ck_[k];
            while (m) {
                const int r0 = __ffsll((long long)m) - 1; m &= m - 1;
                const bool vB = (m != 0);
                const int r1 = vB ? (__ffsll((long long)m) - 1) : r0;
                if (vB) m &= m - 1;

                const float4 pA = pred4[(size_t)(rb + r0) * 64 + lane];
                const float4 pB = pred4[(size_t)(rb + r1) * 64 + lane];

                const float ax = pA.x * ivk, ay = pA.y * ivk;
                const float az = pA.z * ivk, aw = pA.w * ivk;
                const float gb = vB ? ivk : 0.f;   // gate B to zero if invalid
                const float bx = pB.x * gb, by = pB.y * gb;
                const float bz = pB.z * gb, bw = pB.w * gb;

                acc[k].x += ax + bx;
                acc[k].y += ay + by;
                acc[k].z += az + bz;
                acc[k].w += aw + bw;

                float dx = ck.x - ax, dy = ck.y - ay;
                float dz = ck.z - az, dw = ck.w - aw;
                float ssA = dx*dx + dy*dy + dz*dz + dw*dw;
                dx = ck.x - bx; dy = ck.y - by;
                dz = ck.z - bz; dw = ck.w - bw;
                float ssB = dx*dx + dy*dy + dz*dz + dw*dw;

                const float rA = dpp_sum64(ssA);
                const float rB = dpp_sum64(ssB);
                if (lane == 63)
                    sacc[k] += sqrtf(rA) + (vB ? sqrtf(rB) : 0.f);
            }
        }
    }

    // flush (no atomics when P>0)
    if (P > 0) {
        float4* dst = (float4*)(ws + OFF_PART + (size_t)blockIdx.x * CD);
        #pragma unroll
        for (int k = 0; k < 8; ++k)
            dst[(size_t)(cls0 + k) * 64 + lane] = acc[k];
    } else {
        #pragma unroll
        for (int k = 0; k < 8; ++k) {
            const int b = (cls0 + k) * 256 + 4 * lane;
            unsafeAtomicAdd(&ws[b    ], acc[k].x);
            unsafeAtomicAdd(&ws[b + 1], acc[k].y);
            unsafeAtomicAdd(&ws[b + 2], acc[k].z);
            unsafeAtomicAdd(&ws[b + 3], acc[k].w);
        }
    }
    if (lane == 63) {
        #pragma unroll
        for (int k = 0; k < 8; ++k)
            ws[OFF_S + blockIdx.x * 64 + cls0 + k] = sacc[k];
    }
}

__global__ __launch_bounds__(512)
void k2_reduce(const float* __restrict__ cent, const float* __restrict__ count,
               const float* __restrict__ dist, float* __restrict__ ws, int P)
{
    const int tid = threadIdx.x;              // 0..511
    const int sub = tid & 63;
    const int g   = tid >> 6;                 // 0..7
    const int o   = blockIdx.x * 64 + sub;    // element index [c][d], 0..16383

    float sum = 0.f;
    if (P > 0) {
        const float* gp = ws + OFF_PART;
        #pragma unroll 4
        for (int p = g; p < P; p += 8) sum += gp[(size_t)p * CD + o];
    } else if (g == 0) {
        sum = ws[o];
    }
    __shared__ float red[8][64];
    red[g][sub] = sum;
    __syncthreads();

    if (tid < 64) {
        float tot = 0.f;
        #pragma unroll
        for (int q = 0; q < 8; ++q) tot += red[q][tid];
        const int oo = blockIdx.x * 64 + tid;     // direct [c][d] layout
        float val = cent[oo] + tot;               // tot is sum of pr already
        ws[OFF_CENT + oo] = val;
        float a = fabsf(val);
        #pragma unroll
        for (int off = 32; off > 0; off >>= 1) a += __shfl_xor(a, off, 64);
        if (tid == 0) ws[OFF_ABS + blockIdx.x] = a;
    }

    if (blockIdx.x == 0) {
        __shared__ float sred[8][64];
        float ssum = 0.f;
        #pragma unroll 4
        for (int b = g; b < NBLK; b += 8) ssum += ws[OFF_S + b * 64 + sub];
        sred[g][sub] = ssum;
        __syncthreads();
        if (tid < 64) {
            float s_tot = 0.f;
            #pragma unroll
            for (int q = 0; q < 8; ++q) s_tot += sred[q][tid];
            ws[OFF_SF + tid] = sqrtf(dist[tid] + s_tot) / count[tid];
        }
    }
}

__global__ __launch_bounds__(256)
void k3_pairs(const float* __restrict__ cw, float* __restrict__ ws)
{
    const int i    = blockIdx.x;
    const int tid  = threadIdx.x;
    const int lane = tid & 63;
    const int w    = tid >> 6;
    const float4* c4 = (const float4*)(ws + OFF_CENT);
    const float*  sf = ws + OFF_SF;

    float4 ci = c4[i * 64 + lane];
    float  si = sf[i];
    float acc = 0.f;
    for (int j = w; j < NC; j += 4) {
        if (j == i) continue;
        float4 cj = c4[j * 64 + lane];
        float dx = ci.x - cj.x, dy = ci.y - cj.y;
        float dz = ci.z - cj.z, dw = ci.w - cj.w;
        float ss = dx*dx + dy*dy + dz*dz + dw*dw;
        #pragma unroll
        for (int o = 32; o > 0; o >>= 1) ss += __shfl_xor(ss, o, 64);
        float m = sqrtf(ss);
        acc += cw[i * NC + j] * (si + sf[j]) / m;
    }
    __shared__ float wsum[4];
    if (lane == 0) wsum[w] = acc;
    __syncthreads();
    if (tid == 0) ws[OFF_PAIR + i] = wsum[0] + wsum[1] + wsum[2] + wsum[3];
}

__global__ __launch_bounds__(256)
void k4_final(const float* __restrict__ ws, float* __restrict__ out)
{
    const int t = threadIdx.x;   // 256 threads
    float a = ws[OFF_ABS + t];
    float p = (t < 64) ? ws[OFF_PAIR + t] : 0.f;
    #pragma unroll
    for (int o = 32; o > 0; o >>= 1) {
        a += __shfl_xor(a, o, 64);
        p += __shfl_xor(p, o, 64);
    }
    __shared__ float ra[4], rp[4];
    if ((t & 63) == 0) { ra[t >> 6] = a; rp[t >> 6] = p; }
    __syncthreads();
    if (t == 0) {
        float pair_sum = rp[0] + rp[1] + rp[2] + rp[3];
        float abs_sum  = ra[0] + ra[1] + ra[2] + ra[3];
        out[0] = pair_sum / 64.0f * 63.0f + abs_sum * 1e-6f;
    }
}

extern "C" void kernel_launch(void* const* d_in, const int* in_sizes, int n_in,
                              void* d_out, int out_size, void* d_ws, size_t ws_size,
                              hipStream_t stream)
{
    const float* pred  = (const float*)d_in[0];
    const float* cent  = (const float*)d_in[1];
    const float* dist  = (const float*)d_in[2];
    const float* count = (const float*)d_in[3];
    const float* cw    = (const float*)d_in[4];
    const int*   tgt   = (const int*)d_in[5];
    float* ws  = (float*)d_ws;
    float* out = (float*)d_out;

    long ws_f  = (long)(ws_size / sizeof(float));
    long avail = ws_f - OFF_PART;
    int P = (avail >= (long)NBLK * CD) ? NBLK : 0;

    // zero only the atomic-fallback region A (used when P==0)
    hipMemsetAsync(d_ws, 0, (size_t)CD * sizeof(float), stream);

    k1_main<<<NBLK, T1, 0, stream>>>(pred, cent, count, tgt, ws, P);
    k2_reduce<<<256, 512, 0, stream>>>(cent, count, dist, ws, P);
    k3_pairs<<<NC, 256, 0, stream>>>(cw, ws);
    k4_final<<<1, 256, 0, stream>>>(ws, out);
}